// Round 15
// baseline (233.653 us; speedup 1.0000x reference)
//
#include <hip/hip_runtime.h>
#include <cstdint>

#define BB 8
#define CC 128
#define HH 96
#define WW 160
#define HWsz (HH * WW)                 // 15360
#define TH 8
#define TW 32
#define CSTEP 8
#define SW 48                          // LDS row stride in words (40 used + pad)
#define CIW (TH * SW)                  // 384 words per channel slice (8 rows)
#define BUFW (CSTEP * CIW)             // 3072 words = 12 KB per buffer
#define WAVEW (2 * BUFW)               // 6144 words per wave (double buffer)
#define NWAVES 3
#define NTHREADS (NWAVES * 64)         // 192
#define NCHUNKS (CC / CSTEP)           // 16
#define NTILES (BB * (HH / TH) * (WW / TW))   // 480
#define NBLOCKS (NTILES * 3)           // 1440 blocks = (tile, dy-triple)

__device__ __forceinline__ void g2l_dword(const float* g, float* l) {
  __builtin_amdgcn_global_load_lds((const __attribute__((address_space(1))) void*)g,
                                   (__attribute__((address_space(3))) void*)l,
                                   4, 0, 0);
}

// R15: ZERO-BARRIER multi-wave blocks. 15-round synthesis: VALU-busy-time is
// ~28 us in EVERY barriered structure (VALUBusy pinned at ~26%) while walls
// sit at 107-112 us; DS demand, conflicts, FETCH all varied 2-6x with no wall
// change -> the invariant cost is the per-chunk barrier convoy, not any pipe.
// R12 (no barriers, 1-wave blocks) failed from zero intra-SIMD TLP. This fills
// the untested cell: 3-wave blocks (PROVEN 120-124 VGPR budget, R13/14) where
// each wave runs a PRIVATE dy + PRIVATE 2-deep LDS pipeline, never syncing.
//
// Per-wave FIFO discipline (R10 lesson: vmcnt waits drain ALL older):
//   iter k: [A1: stage(k+1) slots 0..31]
//           [W : vmcnt(32)] -> keeps A1's 32, drains stage(k) 64 + pf(k) 8
//           [A2: stage(k+1) slots 32..63]
//           [D : compute(k) — pure LDS + pf regs]
//           [P : pf(k+1) — 8 x1 float4]
// RAW: W(k) retires stage(k) (oldest) before D(k) reads it; pf(k) likewise.
// WAR: A1/A2(k) overwrite buf (k+1)&1, last read by D(k-1) — same wave,
// in-order: those reads were consumed by FMAs (lgkm-waited) before A1 issues.
// The 32/32 split keeps every wait value encodable (vmcnt is 6-bit) and the
// outstanding count near the 63 hardware cap (brief issue throttle, harmless).
extern "C" __global__ void __launch_bounds__(NTHREADS, 2)
corr81_kernel(const float* __restrict__ x1, const float* __restrict__ x2,
              float* __restrict__ out)
{
  __shared__ __align__(16) float lds[NWAVES * WAVEW];   // 73728 B -> 2 blocks/CU

  const int tid  = threadIdx.x;
  const int wvu  = __builtin_amdgcn_readfirstlane(tid >> 6);  // wave 0..2
  const int lane = tid & 63;
  const int r    = lane >> 3;    // tile row 0..7
  const int j    = lane & 7;     // w-slot 0..7 (4 px each)

  // XCD-bijective swizzle (validated: FETCH 184 -> 65 MB). 1440 % 8 == 0.
  const int bid0 = blockIdx.x;
  const int bid  = (bid0 & 7) * (NBLOCKS / 8) + (bid0 >> 3);
  const int tile = bid / 3;
  const int g    = bid - 3 * tile;          // dy-triple index 0..2
  const int wt   = tile % (WW / TW);
  const int ht   = (tile / (WW / TW)) % (HH / TH);
  const int b    = tile / ((WW / TW) * (HH / TH));
  const int h0   = ht * TH;
  const int w0   = wt * TW;
  const int dy   = 3 * g + wvu;             // this wave's dy, 0..8

  // ---- per-wave staging tables. Rows: this wave needs global rows
  // h0+dy-4+row (row 0..7) — its dy folded in, clamped (replicate pad). SGPRs.
  int grw[TH];
#pragma unroll
  for (int row = 0; row < TH; ++row) {
    int v = h0 + dy - 4 + row;
    v = v < 0 ? 0 : (v > HH - 1 ? HH - 1 : v);
    grw[row] = v * WW;
  }
  // Per-lane staged columns per swizzle class m = row&3 (R13-proven involution:
  // phys word l of a row holds logical col l ^ (m<<2); source-permuted). 4 VGPRs.
  int gw[4];
#pragma unroll
  for (int mm = 0; mm < 4; ++mm) {
    const int cl = lane ^ (mm << 2);
    int v = w0 + cl - 4;
    gw[mm] = v < 0 ? 0 : (v > WW - 1 ? WW - 1 : v);
  }

  float* wb = &lds[wvu * WAVEW];            // this wave's private LDS region
  const float* x2b = x2 + (size_t)b * CC * HWsz;
  const float* x1c = x1 + (size_t)b * CC * HWsz
                        + (size_t)(h0 + r) * WW + (w0 + 4 * j);

  float acc[9][4];
#pragma unroll
  for (int d = 0; d < 9; ++d)
#pragma unroll
    for (int p = 0; p < 4; ++p) acc[d][p] = 0.f;

  // x2 LDS read bases: lane (r,j) reads ONLY its own row r (dy pre-folded at
  // staging). m = r&3; logical granules j..j+2 at phys ^m.
  const int m  = r & 3;
  const int B0 = r * SW + (((j + 0) ^ m) << 2);
  const int B1 = r * SW + (((j + 1) ^ m) << 2);
  const int B2 = r * SW + (((j + 2) ^ m) << 2);

  // 64 staging slots per chunk: slot i = (ci = i>>3, row = i&7), 48 lanes.
#define STG(BUF, SRC, LO, HI)                                                \
  if (lane < SW) {                                                          \
    _Pragma("unroll")                                                        \
    for (int i = (LO); i < (HI); ++i) {                                      \
      const int ci = i >> 3, row = i & 7;                                    \
      g2l_dword((SRC) + ci * HWsz + grw[row] + gw[row & 3],                  \
                wb + (BUF) * BUFW + ci * CIW + row * SW);                    \
    }                                                                        \
  }

#define PFL(KP)                                                              \
  {                                                                          \
    const float* xp = x1c + (size_t)(KP) * (CSTEP * HWsz);                   \
    _Pragma("unroll")                                                        \
    for (int q = 0; q < CSTEP; ++q)                                          \
      pf[q] = *(const float4*)(xp + (size_t)q * HWsz);                       \
  }

#define COMPUTE(CB)                                                          \
  {                                                                          \
    const float* xb = wb + (CB) * BUFW;                                      \
    _Pragma("unroll")                                                        \
    for (int ci = 0; ci < CSTEP; ++ci) {                                     \
      const float av[4] = {pf[ci].x, pf[ci].y, pf[ci].z, pf[ci].w};          \
      const float4 f0 = *(const float4*)(xb + ci * CIW + B0);                \
      const float4 f1 = *(const float4*)(xb + ci * CIW + B1);                \
      const float4 f2 = *(const float4*)(xb + ci * CIW + B2);                \
      const float w12[12] = {f0.x, f0.y, f0.z, f0.w, f1.x, f1.y, f1.z,       \
                             f1.w, f2.x, f2.y, f2.z, f2.w};                  \
      _Pragma("unroll")                                                      \
      for (int d = 0; d < 9; ++d)                                            \
        _Pragma("unroll")                                                    \
        for (int p = 0; p < 4; ++p)                                          \
          acc[d][p] = fmaf(av[p], w12[d + p], acc[d][p]);                    \
    }                                                                        \
  }

  float4 pf[CSTEP];   // x1 prefetch, 32 VGPRs, compile-time indexed (rule #20)

  // ---- prologue FIFO: [stage(0) 64][pf(0) 8]
  STG(0, x2b, 0, 64)
  PFL(0)

#pragma unroll 1
  for (int k = 0; k < NCHUNKS - 1; ++k) {
    const float* s2 = x2b + (size_t)(k + 1) * (CSTEP * HWsz);
    const int nb = (k + 1) & 1;

    __builtin_amdgcn_sched_barrier(0);
    STG(nb, s2, 0, 32)                       // [A1]
    __builtin_amdgcn_sched_barrier(0);
    asm volatile("s_waitcnt vmcnt(32)" ::: "memory");   // [W]
    __builtin_amdgcn_sched_barrier(0);
    STG(nb, s2, 32, 64)                      // [A2]
    __builtin_amdgcn_sched_barrier(0);

    COMPUTE(k & 1)                           // [D] pure LDS + pf regs
    PFL(k + 1)                               // [P] newest in FIFO
    __builtin_amdgcn_sched_barrier(0);
  }

  // ---- peeled last chunk (k = 15, buf 1): drain everything
  asm volatile("s_waitcnt vmcnt(0)" ::: "memory");
  __builtin_amdgcn_sched_barrier(0);
  COMPUTE((NCHUNKS - 1) & 1)

  // ---- epilogue: out[((b*81 + dy*9 + d)*H + h0+r)*W + w0+4j], scale 1/8
  float* op = out + (((size_t)b * 81 + (size_t)dy * 9) * HH + (h0 + r)) * WW + (w0 + 4 * j);
#pragma unroll
  for (int d = 0; d < 9; ++d) {
    float4 v;
    v.x = acc[d][0] * 0.125f;
    v.y = acc[d][1] * 0.125f;
    v.z = acc[d][2] * 0.125f;
    v.w = acc[d][3] * 0.125f;
    *(float4*)(op + (size_t)d * HWsz) = v;
  }
}

extern "C" void kernel_launch(void* const* d_in, const int* in_sizes, int n_in,
                              void* d_out, int out_size, void* d_ws, size_t ws_size,
                              hipStream_t stream) {
  const float* x1 = (const float*)d_in[0];
  const float* x2 = (const float*)d_in[1];
  float* out = (float*)d_out;
  corr81_kernel<<<dim3(NBLOCKS), dim3(NTHREADS), 0, stream>>>(x1, x2, out);
}

// Round 16
// 216.633 us; speedup vs baseline: 1.0786x; 1.0786x over previous
//
#include <hip/hip_runtime.h>
#include <cstdint>

#define BB 8
#define CC 128
#define HH 96
#define WW 160
#define HWsz (HH * WW)                 // 15360
#define TH 8
#define TW 32
#define CSTEP 8
#define HROWS 10                       // halo rows for a dy-triple: TH + 2
#define SW 48                          // x2 row stride (40 used + pad), swizzle-closed
#define CIW (HROWS * SW)               // 480 words per channel slice
#define X2W (CSTEP * CIW)              // 3840 words = 15 KB per x2 buffer
#define NWAVES 3
#define NTHREADS (NWAVES * 64)         // 192
#define NCHUNKS (CC / CSTEP)           // 16
#define NTILES (BB * (HH / TH) * (WW / TW))   // 480
#define NBLOCKS (NTILES * 3)           // 1440 blocks = (tile, dy-triple)
// LDS: 2 * X2W = 7680 words = 30720 B -> 5 blocks/CU co-residable (150 KB)

__device__ __forceinline__ void g2l_dword(const float* g, float* l) {
  __builtin_amdgcn_global_load_lds((const __attribute__((address_space(1))) void*)g,
                                   (__attribute__((address_space(3))) void*)l,
                                   4, 0, 0);
}

// R16 = R13 with x1 moved LDS -> register prefetch, shrinking LDS 47->30 KB.
// Theory (R12..R15 synthesis): walls are per-wave latency exposure at ~1.6
// effective blocks/CU; the dispatcher packs ~6 small blocks (R12) but only
// ~1.6 of R13's 47 KB blocks. 30 KB -> 5 co-residable; barriers stay (both
// barrier-free cells regressed: R12 +60%, R15 +38%).
// FIFO discipline (R4/R15-proven): pf(k+1) issued at COMPUTE tail ->
// order [stage(k) 30][pf(k) 8][stage(k+1) 30]; manual vmcnt(38) drains
// stage(k) only; compiler's pf(k)-use wait is vmcnt(30) -> never drains
// stage(k+1). Outstanding peaks 68 > 63: HW throttles issue, harmless.
// 3 waves re-load the same x1 tile (L1-served, R0-proven harmless).
extern "C" __global__ void __launch_bounds__(NTHREADS, 2)
corr81_kernel(const float* __restrict__ x1, const float* __restrict__ x2,
              float* __restrict__ out)
{
  __shared__ __align__(16) float lds[2 * X2W];   // 30720 B

  const int tid  = threadIdx.x;
  const int wvu  = __builtin_amdgcn_readfirstlane(tid >> 6);  // wave 0..2
  const int lane = tid & 63;
  const int r    = lane >> 3;    // tile row 0..7
  const int j    = lane & 7;     // w-slot 0..7 (4 px each)

  // XCD-bijective swizzle (validated): 1440 % 8 == 0.
  const int bid0 = blockIdx.x;
  const int bid  = (bid0 & 7) * (NBLOCKS / 8) + (bid0 >> 3);
  const int tile = bid / 3;
  const int g    = bid - 3 * tile;          // dy-triple index 0..2
  const int wt   = tile % (WW / TW);
  const int ht   = (tile / (WW / TW)) % (HH / TH);
  const int b    = tile / ((WW / TW) * (HH / TH));
  const int h0   = ht * TH;
  const int w0   = wt * TW;
  const int hb   = h0 + 3 * g - 4;          // halo row 0 source row (pre-clamp)

  // ---- scalar staging tables (R13 verbatim; compile-time indexed -> SGPRs).
  int grw[HROWS];
#pragma unroll
  for (int rr = 0; rr < HROWS; ++rr) {
    int v = hb + rr; v = v < 0 ? 0 : (v > HH - 1 ? HH - 1 : v);
    grw[rr] = v * WW;
  }
  int sc2[3], dc2[3];                       // per-channel bases (wave-uniform)
#pragma unroll
  for (int c = 0; c < 3; ++c) {
    int ci = 3 * wvu + c; if (ci >= CSTEP) ci = 6;   // wl=2 remainder redirect
    sc2[c] = ci * HWsz;
    dc2[c] = ci * CIW;
  }

  // ---- per-lane staged columns, one per swizzle class m = row&3 (4 VGPRs).
  int gw[4];
#pragma unroll
  for (int mm = 0; mm < 4; ++mm) {
    const int cl = lane ^ (mm << 2);        // logical col this phys word holds
    int v = w0 + cl - 4;
    gw[mm] = v < 0 ? 0 : (v > WW - 1 ? WW - 1 : v);
  }

  const float* x2b = x2 + (size_t)b * CC * HWsz;
  const float* x1c = x1 + (size_t)b * CC * HWsz
                        + (size_t)(h0 + r) * WW + (w0 + 4 * j);

  float acc[9][4];
#pragma unroll
  for (int d = 0; d < 9; ++d)
#pragma unroll
    for (int p = 0; p < 4; ++p) acc[d][p] = 0.f;

  // x2 LDS read bases (R13 verbatim): R = r + wl, m = R&3.
  const int R  = r + wvu;                   // 0..9
  const int m  = R & 3;
  const int B0 = R * SW + (((j + 0) ^ m) << 2);
  const int B1 = R * SW + (((j + 1) ^ m) << 2);
  const int B2 = R * SW + (((j + 2) ^ m) << 2);

  // 30 x2 staging loads per wave per chunk (c, row both compile-time).
#define STAGE(BUF, S2)                                                       \
  if (lane < SW) {                                                          \
    float* d2 = &lds[(BUF) * X2W];                                           \
    _Pragma("unroll")                                                        \
    for (int i = 0; i < 30; ++i) {                                           \
      const int c = i / 10, row = i % 10;                                    \
      g2l_dword((S2) + sc2[c] + grw[row] + gw[row & 3],                      \
                d2 + dc2[c] + row * SW);                                     \
    }                                                                        \
  }

#define PFL(KP)                                                              \
  {                                                                          \
    const float* xp = x1c + (size_t)(KP) * (CSTEP * HWsz);                   \
    _Pragma("unroll")                                                        \
    for (int q = 0; q < CSTEP; ++q)                                          \
      pf[q] = *(const float4*)(xp + (size_t)q * HWsz);                       \
  }

#define COMPUTE(CB)                                                          \
  {                                                                          \
    const float* xb = &lds[(CB) * X2W];                                      \
    _Pragma("unroll")                                                        \
    for (int ci = 0; ci < CSTEP; ++ci) {                                     \
      const float av[4] = {pf[ci].x, pf[ci].y, pf[ci].z, pf[ci].w};          \
      const float4 f0 = *(const float4*)(xb + B0 + ci * CIW);                \
      const float4 f1 = *(const float4*)(xb + B1 + ci * CIW);                \
      const float4 f2 = *(const float4*)(xb + B2 + ci * CIW);                \
      const float w12[12] = {f0.x, f0.y, f0.z, f0.w, f1.x, f1.y, f1.z,       \
                             f1.w, f2.x, f2.y, f2.z, f2.w};                  \
      _Pragma("unroll")                                                      \
      for (int d = 0; d < 9; ++d)                                            \
        _Pragma("unroll")                                                    \
        for (int p = 0; p < 4; ++p)                                          \
          acc[d][p] = fmaf(av[p], w12[d + p], acc[d][p]);                    \
    }                                                                        \
  }

  float4 pf[CSTEP];   // x1 prefetch, 32 VGPRs, compile-time indexed (rule #20)

  // ---- prologue FIFO: [stage(0) 30][pf(0) 8]
  STAGE(0, x2b)
  PFL(0)

#pragma unroll 1
  for (int k = 0; k < NCHUNKS - 1; ++k) {
    // [A] issue stage(k+1)
    {
      const float* s2 = x2b + (size_t)(k + 1) * (CSTEP * HWsz);
      __builtin_amdgcn_sched_barrier(0);
      STAGE((k + 1) & 1, s2)
      __builtin_amdgcn_sched_barrier(0);
    }

    // [B] drains stage(k) 30 (+ older); keeps pf(k) 8 + stage(k+1) 30 = 38
    asm volatile("s_waitcnt vmcnt(38)" ::: "memory");
    __builtin_amdgcn_sched_barrier(0);
    __builtin_amdgcn_s_barrier();             // cross-wave RAW (shared halo)
    __builtin_amdgcn_sched_barrier(0);

    // [D] compute chunk k: 24 ds_read_b128 + 288 FMA; x1 from pf regs
    COMPUTE(k & 1)
    // tail: pf(k+1) — lands after stage(k+1) in FIFO (any reorder stays safe)
    PFL(k + 1)
    __builtin_amdgcn_sched_barrier(0);

    // [C2] WAR barrier
    __builtin_amdgcn_s_barrier();
    __builtin_amdgcn_sched_barrier(0);
  }

  // ---- peeled last chunk (k = 15, buf 1): drain everything
  asm volatile("s_waitcnt vmcnt(0)" ::: "memory");
  __builtin_amdgcn_sched_barrier(0);
  __builtin_amdgcn_s_barrier();
  __builtin_amdgcn_sched_barrier(0);
  COMPUTE(1)

  // ---- epilogue (R13 verbatim): dy = 3g + wl
  const int dy = 3 * g + wvu;
  float* op = out + (((size_t)b * 81 + (size_t)dy * 9) * HH + (h0 + r)) * WW + (w0 + 4 * j);
#pragma unroll
  for (int d = 0; d < 9; ++d) {
    float4 v;
    v.x = acc[d][0] * 0.125f;
    v.y = acc[d][1] * 0.125f;
    v.z = acc[d][2] * 0.125f;
    v.w = acc[d][3] * 0.125f;
    *(float4*)(op + (size_t)d * HWsz) = v;
  }
}

extern "C" void kernel_launch(void* const* d_in, const int* in_sizes, int n_in,
                              void* d_out, int out_size, void* d_ws, size_t ws_size,
                              hipStream_t stream) {
  const float* x1 = (const float*)d_in[0];
  const float* x2 = (const float*)d_in[1];
  float* out = (float*)d_out;
  corr81_kernel<<<dim3(NBLOCKS), dim3(NTHREADS), 0, stream>>>(x1, x2, out);
}

// Round 17
// 202.923 us; speedup vs baseline: 1.1514x; 1.0676x over previous
//
#include <hip/hip_runtime.h>
#include <cstdint>

#define BB 8
#define CC 128
#define HH 96
#define WW 160
#define HWsz (HH * WW)                 // 15360
#define TH 8
#define TW 32
#define CSTEP 8
#define HROWS 10                       // halo rows for a dy-triple: TH + 2
#define SW 48                          // x2 row stride (words): 12 four-word blocks
#define CIW (HROWS * SW)               // 480 words per channel slice
#define X2W (CSTEP * CIW)              // 3840 words = 15 KB per x2 buffer
#define X1W (CSTEP * TH * TW)          // 2048 words = 8 KB per x1 buffer
#define NWAVES 3
#define NTHREADS (NWAVES * 64)         // 192
#define NCHUNKS (CC / CSTEP)           // 16
#define NTILES (BB * (HH / TH) * (WW / TW))   // 480
#define NBLOCKS (NTILES * 3)           // 1440 blocks = (tile, dy-triple)
#define X1B (2 * X2W)                  // x1 region base: 7680 words
// LDS: 2*X2W + 2*X1W = 11776 words = 47104 B (R14-identical layout)

__device__ __forceinline__ void g2l_16(const float* g, float* l) {
  __builtin_amdgcn_global_load_lds((const __attribute__((address_space(1))) void*)g,
                                   (__attribute__((address_space(3))) void*)l,
                                   16, 0, 0);   // width 16: lane i -> dst + 16*i
}

// R17 = R14 with staging width 4 -> 16 (global_load_lds_dwordx4).
// Theory (17-round synthesis): every structure pins at ~5-6 effective
// waves/CU with no pipe >40% busy; the invariant is width-4 staging holding
// 38-84 outstanding vmem requests/wave -- ABOVE the 63 vmcnt cap (R14 peaks
// at 84: issue-stall every chunk) and saturating the CU's shared request
// queue, serializing waves at vmem issue regardless of barrier structure.
// Width-16: 8 requests/wave/chunk (5 x2 + 3 x1), peak outstanding 16.
// Guide ladder: this exact change was +67% on GEMM (m93->m97).
// LDS layout, swizzle, schedule, compute, epilogue: R14 VERBATIM. The 16-B
// lane granularity matches the 4-word XOR swizzle block exactly, so the
// source permutation is unchanged. Only per-WORD column clamping is lost:
// edge tiles (wt==0: logical block 0 = cols -4..-1; wt==4: block 9 = cols
// 160..163) get a block-clamped (garbage) stage + an LDS fixup (broadcast
// the clamp column) after the barrier, before compute. Row clamping is
// uniform per row -> unaffected. Interior tiles (60%) need no fixup.
extern "C" __global__ void __launch_bounds__(NTHREADS, 2)
corr81_kernel(const float* __restrict__ x1, const float* __restrict__ x2,
              float* __restrict__ out)
{
  __shared__ __align__(16) float lds[2 * X2W + 2 * X1W];   // 47104 B

  const int tid  = threadIdx.x;
  const int wvu  = __builtin_amdgcn_readfirstlane(tid >> 6);  // wave 0..2
  const int lane = tid & 63;
  const int h    = lane >> 5;        // channel-half: ci = 4h..4h+3
  const int r    = (lane >> 2) & 7;  // tile row 0..7
  const int s    = lane & 3;         // 8-px col slot (cols 8s..8s+7)

  // XCD-bijective swizzle (validated): 1440 % 8 == 0.
  const int bid0 = blockIdx.x;
  const int bid  = (bid0 & 7) * (NBLOCKS / 8) + (bid0 >> 3);
  const int tile = bid / 3;
  const int g    = bid - 3 * tile;          // dy-triple index 0..2
  const int wt   = tile % (WW / TW);
  const int ht   = (tile / (WW / TW)) % (HH / TH);
  const int b    = tile / ((WW / TW) * (HH / TH));
  const int h0   = ht * TH;
  const int w0   = wt * TW;
  const int hb   = h0 + 3 * g - 4;          // halo row 0 source row (pre-clamp)

  // ---- x2 staging: 15 slots of 256 LDS words; slot sl = wvu + 3i (5/wave).
  // Lane covers words sl*256 + 4*lane .. +3 = one 4-word block of the R14
  // layout [ci][row][48]. Per-lane source offset precomputed ONCE (R2 lesson),
  // with block-level clamps (edges fixed up post-stage).
  int soff2[5];
#pragma unroll
  for (int i = 0; i < 5; ++i) {
    const int sl  = wvu + 3 * i;
    const int w   = sl * 256 + 4 * lane;
    const int ci  = w / CIW;
    const int rem = w - ci * CIW;
    const int row = rem / SW;
    const int blk = (rem - row * SW) >> 2;
    int gh = hb + row; gh = gh < 0 ? 0 : (gh > HH - 1 ? HH - 1 : gh);
    int gc = w0 - 4 + 4 * (blk ^ (row & 3));          // source-permuted col
    gc = gc < 0 ? 0 : (gc > WW - 4 ? WW - 4 : gc);    // block clamp (safety)
    soff2[i] = ci * HWsz + gh * WW + gc;
  }
  // ---- x1 staging: 8 slots of 256 words (slot = channel); per-lane part
  // shared by all slots. Wave2's third slot redirects 8 -> 5 (same src+dst,
  // benign same-wave dup) keeping 3 loads/wave uniform for vmcnt math.
  const int xr  = lane >> 3;               // x1 row 0..7
  const int xbk = lane & 7;                // phys block 0..7
  const int off1 = (h0 + xr) * WW + w0 + 4 * (xbk ^ (xr & 3));
  int slx[3];
#pragma unroll
  for (int i = 0; i < 3; ++i) {
    int sl = wvu + 3 * i; if (sl >= 8) sl = 5;
    slx[i] = sl;
  }

  // ---- edge fixup tables (wt==0 or wt==4), per-lane, computed once.
  // Pair p = (ci, row) = (p/10, p%10); lane handles p=lane and p=64+lane(<80).
  const bool doFix = (wt == 0) || (wt == (WW / TW - 1));
  const int Lsrc = (wt == 0) ? 1 : 8;      // logical block holding clamp col
  const int wsrc = (wt == 0) ? 0 : 3;      // word within it (col 0 / col 159)
  const int Ldst = (wt == 0) ? 0 : 9;      // logical block to broadcast into
  int fixS1, fixD1, fixS2, fixD2;
  {
    const int p1 = lane;      const int c1 = p1 / 10, r1 = p1 - 10 * c1;
    fixS1 = c1 * CIW + r1 * SW + 4 * (Lsrc ^ (r1 & 3)) + wsrc;
    fixD1 = c1 * CIW + r1 * SW + 4 * (Ldst ^ (r1 & 3));
    const int p2 = 64 + lane; const int c2 = p2 / 10, r2 = p2 - 10 * c2;
    fixS2 = c2 * CIW + r2 * SW + 4 * (Lsrc ^ (r2 & 3)) + wsrc;
    fixD2 = c2 * CIW + r2 * SW + 4 * (Ldst ^ (r2 & 3));
  }

  const float* x2b = x2 + (size_t)b * CC * HWsz;
  const float* x1b = x1 + (size_t)b * CC * HWsz;

  float acc[9][8];
#pragma unroll
  for (int d = 0; d < 9; ++d)
#pragma unroll
    for (int p = 0; p < 8; ++p) acc[d][p] = 0.f;

  // ---- read bases (R14 verbatim).
  const int R  = r + wvu;                   // 0..9
  const int m2 = R & 3;
  int B4[4];
#pragma unroll
  for (int t = 0; t < 4; ++t)
    B4[t] = h * (4 * CIW) + R * SW + (((2 * s + t) ^ m2) << 2);
  const int m1 = r & 3;
  const int A0 = h * 1024 + r * TW + (((2 * s + 0) ^ m1) << 2);
  const int A1 = h * 1024 + r * TW + (((2 * s + 1) ^ m1) << 2);

#define STAGE(BUF, S2, S1)                                                   \
  {                                                                          \
    float* d2 = &lds[(BUF) * X2W];                                           \
    _Pragma("unroll")                                                        \
    for (int i = 0; i < 5; ++i)                                              \
      g2l_16((S2) + soff2[i], d2 + (wvu + 3 * i) * 256);                     \
    float* d1 = &lds[X1B + (BUF) * X1W];                                     \
    _Pragma("unroll")                                                        \
    for (int i = 0; i < 3; ++i)                                              \
      g2l_16((S1) + slx[i] * HWsz + off1, d1 + slx[i] * 256);                \
  }

#define FIXUP(CB)                                                            \
  if (doFix) {                                                               \
    float* fb = &lds[(CB) * X2W];                                            \
    const float v1 = fb[fixS1];                                              \
    float4 q1; q1.x = v1; q1.y = v1; q1.z = v1; q1.w = v1;                   \
    *(float4*)(fb + fixD1) = q1;                                             \
    if (lane < 16) {                                                         \
      const float v2 = fb[fixS2];                                            \
      float4 q2; q2.x = v2; q2.y = v2; q2.z = v2; q2.w = v2;                 \
      *(float4*)(fb + fixD2) = q2;                                           \
    }                                                                        \
  }

#define COMPUTE(CB)                                                          \
  {                                                                          \
    const float* xb = &lds[(CB) * X2W];                                      \
    const float* ab = &lds[X1B + (CB) * X1W];                                \
    _Pragma("unroll")                                                        \
    for (int q = 0; q < 4; ++q) {        /* ci = 4h + q */                   \
      const float4 a0 = *(const float4*)(ab + A0 + q * 256);                 \
      const float4 a1 = *(const float4*)(ab + A1 + q * 256);                 \
      const float av[8] = {a0.x, a0.y, a0.z, a0.w, a1.x, a1.y, a1.z, a1.w};  \
      float w16[16];                                                         \
      _Pragma("unroll")                                                      \
      for (int t = 0; t < 4; ++t) {                                          \
        const float4 f = *(const float4*)(xb + B4[t] + q * CIW);             \
        w16[4*t+0] = f.x; w16[4*t+1] = f.y;                                  \
        w16[4*t+2] = f.z; w16[4*t+3] = f.w;                                  \
      }                                                                      \
      _Pragma("unroll")                                                      \
      for (int d = 0; d < 9; ++d)                                            \
        _Pragma("unroll")                                                    \
        for (int p = 0; p < 8; ++p)                                          \
          acc[d][p] = fmaf(av[p], w16[d + p], acc[d][p]);                    \
    }                                                                        \
  }

  // ---- prologue: stage chunk 0 into buffer 0 (8 width-16 loads/wave)
  STAGE(0, x2b, x1b)

#pragma unroll 1
  for (int k = 0; k < NCHUNKS - 1; ++k) {
    // [A] issue stage(k+1)
    {
      const float* s2 = x2b + (size_t)(k + 1) * (CSTEP * HWsz);
      const float* s1 = x1b + (size_t)(k + 1) * (CSTEP * HWsz);
      STAGE((k + 1) & 1, s2, s1)
    }

    // [B] counted wait: drains stage(k)'s 8, keeps stage(k+1)'s 8 in flight.
    // Peak outstanding = 16 << 63 cap (vs R14's 84: issue-stall eliminated).
    __builtin_amdgcn_sched_barrier(0);
    asm volatile("s_waitcnt vmcnt(8)" ::: "memory");
    __builtin_amdgcn_sched_barrier(0);
    __builtin_amdgcn_s_barrier();
    __builtin_amdgcn_sched_barrier(0);

    // [F] edge-column fixup (in-order DS pipe: per-wave write->read safe;
    //     cross-wave writes are identical bytes, benign)
    FIXUP(k & 1)
    __builtin_amdgcn_sched_barrier(0);

    // [D] compute chunk k: 16 x2 + 8 x1 ds_read_b128, 576 FMA per lane
    COMPUTE(k & 1)

    // [C2] WAR barrier
    __builtin_amdgcn_sched_barrier(0);
    __builtin_amdgcn_s_barrier();
    __builtin_amdgcn_sched_barrier(0);
  }

  // ---- peeled last chunk (k = 15, buf 1)
  asm volatile("s_waitcnt vmcnt(0)" ::: "memory");
  __builtin_amdgcn_sched_barrier(0);
  __builtin_amdgcn_s_barrier();
  __builtin_amdgcn_sched_barrier(0);
  FIXUP(1)
  __builtin_amdgcn_sched_barrier(0);
  COMPUTE(1)

  // ---- epilogue (R14 verbatim): combine channel-halves across lane^32, /8.
  const int dy = 3 * g + wvu;
  float* op = out + (((size_t)b * 81 + (size_t)dy * 9) * HH + (h0 + r)) * WW
                  + (w0 + 8 * s + 4 * h);
#pragma unroll
  for (int d = 0; d < 9; ++d) {
    const float own0 = h ? acc[d][4] : acc[d][0];
    const float own1 = h ? acc[d][5] : acc[d][1];
    const float own2 = h ? acc[d][6] : acc[d][2];
    const float own3 = h ? acc[d][7] : acc[d][3];
    const float snd0 = h ? acc[d][0] : acc[d][4];
    const float snd1 = h ? acc[d][1] : acc[d][5];
    const float snd2 = h ? acc[d][2] : acc[d][6];
    const float snd3 = h ? acc[d][3] : acc[d][7];
    float4 v;
    v.x = (own0 + __shfl_xor(snd0, 32)) * 0.125f;
    v.y = (own1 + __shfl_xor(snd1, 32)) * 0.125f;
    v.z = (own2 + __shfl_xor(snd2, 32)) * 0.125f;
    v.w = (own3 + __shfl_xor(snd3, 32)) * 0.125f;
    *(float4*)(op + (size_t)d * HWsz) = v;
  }
}

extern "C" void kernel_launch(void* const* d_in, const int* in_sizes, int n_in,
                              void* d_out, int out_size, void* d_ws, size_t ws_size,
                              hipStream_t stream) {
  const float* x1 = (const float*)d_in[0];
  const float* x2 = (const float*)d_in[1];
  float* out = (float*)d_out;
  corr81_kernel<<<dim3(NBLOCKS), dim3(NTHREADS), 0, stream>>>(x1, x2, out);
}